// Round 17
// baseline (196.812 us; speedup 1.0000x reference)
//
#include <hip/hip_runtime.h>

typedef _Float16 half8 __attribute__((ext_vector_type(8)));
typedef _Float16 half4 __attribute__((ext_vector_type(4)));
typedef float    f32x4 __attribute__((ext_vector_type(4)));

#define W_CLS 16
#define SHOT  8
#define C_CH  128
#define HW    1024
#define NSAMP (SHOT*HW)   /* 8192 */
#define B_Q   256
#define KSPL  32           /* cova K-splits (K=256 per block) */

// async global->LDS, 16B per lane; LDS dest = wave-uniform base (+lane*16 by HW)
__device__ __forceinline__ void gload_lds16(const _Float16* g, _Float16* l) {
    __builtin_amdgcn_global_load_lds((const __attribute__((address_space(1))) unsigned int*)g,
                                     (__attribute__((address_space(3))) unsigned int*)l,
                                     16, 0, 0);
}

// ================= primary path =================

// ---- cova: per (w, k-split) partial gram via fp16 MFMA + mean partials --------
// grid 512 = 16 w x 32 ks (K=256 per block -> 2 blocks/CU), block 512; fp16 PG.
__global__ __launch_bounds__(512) void cova_kernel(const float* __restrict__ x2,
                                                   _Float16* __restrict__ PGh,
                                                   float* __restrict__ pmean) {
    __shared__ _Float16 XT[2][128*72];
    __shared__ float mred[128][4];
    int tid = threadIdx.x;

    int w = blockIdx.x >> 5, ks = blockIdx.x & 31;
    int s = ks >> 2, p00 = (ks & 3) * 256;
    int c = tid >> 2, ph = (tid & 3) * 16;
    const float* src = x2 + (((size_t)(w*SHOT + s))*C_CH + c)*HW + p00 + ph;
    int lane = tid & 63, wv = tid >> 6;
    int lr = lane & 15, lg = lane >> 4;
    int mt0 = (wv & 3)*2, nt0 = (wv >> 2)*4;

    float msum = 0.f;
    f32x4 acc[2][4];
    #pragma unroll
    for (int mm = 0; mm < 2; ++mm)
        #pragma unroll
        for (int nn = 0; nn < 4; ++nn) acc[mm][nn] = (f32x4){0.f,0.f,0.f,0.f};

    float4 rg[4];
    #pragma unroll
    for (int j = 0; j < 4; ++j) rg[j] = *(const float4*)(src + j*4);
    #pragma unroll
    for (int j = 0; j < 4; ++j) {
        msum += rg[j].x + rg[j].y + rg[j].z + rg[j].w;
        half4 h = {(_Float16)rg[j].x, (_Float16)rg[j].y, (_Float16)rg[j].z, (_Float16)rg[j].w};
        *(half4*)(&XT[0][c*72 + ph + j*4]) = h;
    }
    __syncthreads();

    for (int ch = 0; ch < 4; ++ch) {
        int buf = ch & 1;
        if (ch < 3) {
            #pragma unroll
            for (int j = 0; j < 4; ++j) rg[j] = *(const float4*)(src + (ch+1)*64 + j*4);
        }
        const _Float16* xb = XT[buf];
        #pragma unroll
        for (int kk = 0; kk < 2; ++kk) {
            half8 Bv[4], Av[2];
            #pragma unroll
            for (int nn = 0; nn < 4; ++nn)
                Bv[nn] = *(const half8*)(xb + ((nt0+nn)*16 + lr)*72 + kk*32 + lg*8);
            #pragma unroll
            for (int mm = 0; mm < 2; ++mm)
                Av[mm] = *(const half8*)(xb + ((mt0+mm)*16 + lr)*72 + kk*32 + lg*8);
            #pragma unroll
            for (int mm = 0; mm < 2; ++mm)
                #pragma unroll
                for (int nn = 0; nn < 4; ++nn)
                    acc[mm][nn] = __builtin_amdgcn_mfma_f32_16x16x32_f16(Av[mm], Bv[nn], acc[mm][nn], 0,0,0);
        }
        if (ch < 3) {
            #pragma unroll
            for (int j = 0; j < 4; ++j) {
                msum += rg[j].x + rg[j].y + rg[j].z + rg[j].w;
                half4 h = {(_Float16)rg[j].x, (_Float16)rg[j].y, (_Float16)rg[j].z, (_Float16)rg[j].w};
                *(half4*)(&XT[buf^1][c*72 + ph + j*4]) = h;
            }
        }
        __syncthreads();
    }

    mred[c][tid & 3] = msum;
    __syncthreads();
    if (tid < 128)
        pmean[((size_t)w*KSPL + ks)*128 + tid] = mred[tid][0]+mred[tid][1]+mred[tid][2]+mred[tid][3];

    _Float16* pg = PGh + ((size_t)w*KSPL + ks)*16384;
    #pragma unroll
    for (int mm = 0; mm < 2; ++mm)
        #pragma unroll
        for (int nn = 0; nn < 4; ++nn)
            #pragma unroll
            for (int r = 0; r < 4; ++r) {
                int cr = (mt0+mm)*16 + lg*4 + r;
                int d  = (nt0+nn)*16 + lr;
                pg[cr*128 + d] = (_Float16)acc[mm][nn][r];
            }
}

// ---- qcr: blocks 0..255 = per-b fused rnorm + normalize + fp16 fragment repack;
// ----      blocks 256..383 = cova_reduce (overlaps with qconv's BW phase).
__global__ __launch_bounds__(512) void qcr_kernel(const float* __restrict__ x1,
                                                  _Float16* __restrict__ qf,
                                                  const _Float16* __restrict__ PGh,
                                                  const float* __restrict__ pmean,
                                                  _Float16* __restrict__ Uh) {
    if (blockIdx.x >= 256) {
        // ------------- cova_reduce part (512 threads) -------------
        __shared__ float ms[128];
        int t = threadIdx.x;
        int bid = blockIdx.x - 256;
        int w = bid >> 3, rg = bid & 7;
        if (t < 128) {
            float sum = 0.f;
            for (int ks = 0; ks < KSPL; ++ks) sum += pmean[((size_t)w*KSPL + ks)*128 + t];
            ms[t] = sum * (1.0f/NSAMP);
        }
        __syncthreads();
        const _Float16* pg = PGh + (size_t)w*KSPL*16384;
        #pragma unroll
        for (int it = 0; it < 4; ++it) {
            int e = it*512 + t;
            int r = rg*16 + (e >> 7), d = e & 127;
            float g = 0.f;
            for (int ks = 0; ks < KSPL; ++ks) g += (float)pg[(size_t)ks*16384 + r*128 + d];
            float val = (g - (float)NSAMP*ms[r]*ms[d]) * (1.0f/(NSAMP-1));
            float uval = (d > r) ? val : ((d == r) ? 0.5f*val : 0.0f);
            Uh[((size_t)w*128 + r)*128 + d] = (_Float16)uval;
        }
        return;
    }

    // ------------- qconv part: one block per b, rn computed in-block -------------
    __shared__ _Float16 T[128*258];
    __shared__ float rnL[128];
    int tid = threadIdx.x, lane = tid & 63, wv = tid >> 6;
    int b = blockIdx.x;
    const float* xb = x1 + (size_t)b * C_CH * HW;

    // pass A: rn per channel (full-row square sums), x1 slab -> L2
    #pragma unroll
    for (int cc = 0; cc < 16; ++cc) {
        int c = wv*16 + cc;
        const f32x4* row = (const f32x4*)(xb + (size_t)c * HW);
        float s = 0.f;
        #pragma unroll
        for (int j = 0; j < 4; ++j) {
            f32x4 v = row[lane + j*64];
            s += v[0]*v[0] + v[1]*v[1] + v[2]*v[2] + v[3]*v[3];
        }
        #pragma unroll
        for (int off = 32; off; off >>= 1) s += __shfl_xor(s, off, 64);
        if (lane == 0) rnL[c] = 1.0f / sqrtf(s);
    }
    __syncthreads();

    // pass B: per 256-px chunk (L2-hot re-read): stage normalized fp16, emit frags
    for (int ic = 0; ic < 4; ++ic) {
        #pragma unroll
        for (int cc = 0; cc < 16; ++cc) {
            int c = wv*16 + cc;
            f32x4 v = *(const f32x4*)(xb + (size_t)c * HW + ic*256 + lane*4);
            float sc = rnL[c];
            half4 h = {(_Float16)(v[0]*sc), (_Float16)(v[1]*sc),
                       (_Float16)(v[2]*sc), (_Float16)(v[3]*sc)};
            *(half4*)(&T[c*258 + lane*4]) = h;
        }
        __syncthreads();
        #pragma unroll
        for (int it = 0; it < 8; ++it) {
            int slot = it*512 + tid;          // 16 tiles x 4 kk x 64 lanes
            int tl = slot >> 8;
            int kk = (slot >> 6) & 3;
            int ln = slot & 63;
            int i_loc = tl*16 + (ln & 15);
            int c0 = kk*32 + (ln >> 4)*8;
            half8 pk;
            #pragma unroll
            for (int e = 0; e < 8; ++e) pk[e] = T[(c0+e)*258 + i_loc];
            *(half8*)(qf + (((size_t)b*64 + ic*16 + tl)*4 + kk)*512 + ln*8) = pk;
        }
        __syncthreads();
    }
}

// ---- sim (R15 loop verbatim; only change: 4 blocks/CU residency so grid 1024
// is exactly one residency generation -> no 1/3-throughput tail).
// grid 1024: b = bid&255 (4 readers of b -> same XCD), wg = bid>>8 -> w-quad.
#define TR 4
__global__ __launch_bounds__(256, 4) void sim_kernel(const _Float16* __restrict__ qf,
                                                     const _Float16* __restrict__ Uh,
                                                     float* __restrict__ out) {
    __shared__ _Float16 stage[2][TR*2048];     // 2 x 16 KB
    int tid = threadIdx.x, lane = tid & 63, wv = tid >> 6;
    int lr = lane & 15, lg = lane >> 4;
    int b = blockIdx.x & 255, wg = blockIdx.x >> 8;
    int w = wg*4 + wv;

    // A: 20 upper-triangular fragments (m <= 2kk+1), loaded once, L2-resident
    half8 A[20];
    {
        const _Float16* Ub = Uh + (size_t)w*C_CH*C_CH + (size_t)lr*C_CH + lg*8;
        int idx = 0;
        #pragma unroll
        for (int kk = 0; kk < 4; ++kk)
            #pragma unroll
            for (int m = 0; m <= 2*kk+1; ++m) {
                A[idx] = *(const half8*)(Ub + (size_t)m*16*C_CH + kk*32);
                ++idx;
            }
    }

    const _Float16* qfb = qf + (size_t)b * 131072;   // 64 tiles * 2048 halves

    // prologue: stage round 0 -> buf 0 (256 thr x 4 x 16B = 16KB)
    #pragma unroll
    for (int k = 0; k < 4; ++k)
        gload_lds16(qfb + tid*8 + k*2048, &stage[0][tid*8 + k*2048]);
    __syncthreads();

    int offD0 = (lg>>1)*128 + lr*8 + (lg&1)*4;   // + (m>>1)*512 + (m&1)*256
    float* ob = out + ((size_t)b*W_CLS + w)*HW;
    int cur = 0;

    for (int r = 0; r < 16; ++r) {
        if (r < 15) {
            const _Float16* gsrc = qfb + (size_t)(r+1)*(TR*2048);
            #pragma unroll
            for (int k = 0; k < 4; ++k)
                gload_lds16(gsrc + tid*8 + k*2048, &stage[cur^1][tid*8 + k*2048]);
        }
        #pragma unroll
        for (int ti = 0; ti < TR; ++ti) {
            const _Float16* tb = &stage[cur][ti*2048];
            half8 B[4];
            #pragma unroll
            for (int kk = 0; kk < 4; ++kk)
                B[kk] = *(const half8*)(tb + kk*512 + lane*8);
            half4 D[8];
            #pragma unroll
            for (int m = 0; m < 8; ++m)
                D[m] = *(const half4*)(tb + (m>>1)*512 + (m&1)*256 + offD0);
            f32x4 acc[8];
            #pragma unroll
            for (int m = 0; m < 8; ++m) acc[m] = (f32x4){0.f,0.f,0.f,0.f};
            __builtin_amdgcn_s_setprio(1);
            {
                int idx = 0;
                #pragma unroll
                for (int kk = 0; kk < 4; ++kk)
                    #pragma unroll
                    for (int m = 0; m <= 2*kk+1; ++m) {
                        acc[m] = __builtin_amdgcn_mfma_f32_16x16x32_f16(A[idx], B[kk], acc[m], 0, 0, 0);
                        ++idx;
                    }
            }
            __builtin_amdgcn_s_setprio(0);
            // diag tail: 4 independent partials + tree combine (short dep chain)
            float p0 = 0.f, p1 = 0.f, p2 = 0.f, p3 = 0.f;
            #pragma unroll
            for (int m = 0; m < 8; ++m) {
                p0 = fmaf((float)D[m][0], acc[m][0], p0);
                p1 = fmaf((float)D[m][1], acc[m][1], p1);
                p2 = fmaf((float)D[m][2], acc[m][2], p2);
                p3 = fmaf((float)D[m][3], acc[m][3], p3);
            }
            float s = (p0 + p1) + (p2 + p3);
            s += __shfl_xor(s, 16, 64);
            s += __shfl_xor(s, 32, 64);
            if (lane < 16) ob[(r*TR + ti)*16 + lr] = 2.0f * s;
        }
        __syncthreads();   // all waves done with buf cur; next-round stage landed
        cur ^= 1;
    }
}
#undef TR

// ================= fallback path (small ws) =================

__global__ __launch_bounds__(256) void rnorm_kernel(const float* __restrict__ x1,
                                                    float* __restrict__ rn) {
    int row  = blockIdx.x * 4 + (threadIdx.x >> 6);
    int lane = threadIdx.x & 63;
    const float4* p = (const float4*)(x1 + (size_t)row * HW);
    float s = 0.f;
    #pragma unroll
    for (int it = 0; it < 4; ++it) {
        float4 v = p[lane + it * 64];
        s += v.x*v.x + v.y*v.y + v.z*v.z + v.w*v.w;
    }
    for (int off = 32; off; off >>= 1) s += __shfl_down(s, off, 64);
    if (lane == 0) rn[row] = 1.0f / sqrtf(s);
}

__global__ __launch_bounds__(256) void mean_kernel_f(const float* __restrict__ x2,
                                                     float* __restrict__ mean) {
    int wc = blockIdx.x;
    int w  = wc >> 7, c = wc & 127;
    const float* base = x2 + ((size_t)(w * SHOT) * C_CH + c) * HW;
    int tid = threadIdx.x;
    float sum = 0.f;
    for (int s = 0; s < SHOT; ++s) {
        const float* row = base + (size_t)s * C_CH * HW;
        for (int p = tid; p < HW; p += 256) sum += row[p];
    }
    for (int off = 32; off; off >>= 1) sum += __shfl_down(sum, off, 64);
    __shared__ float red[4];
    int lane = tid & 63, wv = tid >> 6;
    if (lane == 0) red[wv] = sum;
    __syncthreads();
    if (tid == 0) mean[wc] = (red[0] + red[1] + red[2] + red[3]) * (1.0f / NSAMP);
}

__global__ __launch_bounds__(256) void cova_kernel_f(const float* __restrict__ x2,
                                                     const float* __restrict__ mean,
                                                     _Float16* __restrict__ covah) {
    int bid = blockIdx.x;
    int w  = bid >> 4;
    int c0 = ((bid >> 2) & 3) * 32;
    int d0 = (bid & 3) * 32;
    __shared__ float As[32][33];
    __shared__ float Bs[32][33];
    int tid = threadIdx.x;
    int ty = tid >> 4, tx = tid & 15;
    int lrr = tid >> 3, lc = (tid & 7) * 4;
    const float* base = x2 + (size_t)w * SHOT * C_CH * HW;
    float acc00 = 0.f, acc01 = 0.f, acc10 = 0.f, acc11 = 0.f;
    for (int k0 = 0; k0 < NSAMP; k0 += 32) {
        int s = k0 >> 10, p = k0 & 1023;
        const float4 a4 = *(const float4*)(base + ((size_t)s * C_CH + (c0 + lrr)) * HW + p + lc);
        const float4 b4 = *(const float4*)(base + ((size_t)s * C_CH + (d0 + lrr)) * HW + p + lc);
        As[lrr][lc+0] = a4.x; As[lrr][lc+1] = a4.y; As[lrr][lc+2] = a4.z; As[lrr][lc+3] = a4.w;
        Bs[lrr][lc+0] = b4.x; Bs[lrr][lc+1] = b4.y; Bs[lrr][lc+2] = b4.z; Bs[lrr][lc+3] = b4.w;
        __syncthreads();
        #pragma unroll
        for (int kk = 0; kk < 32; ++kk) {
            float a0 = As[ty*2][kk],   a1 = As[ty*2+1][kk];
            float b0 = Bs[tx*2][kk],   b1 = Bs[tx*2+1][kk];
            acc00 = fmaf(a0, b0, acc00);
            acc01 = fmaf(a0, b1, acc01);
            acc10 = fmaf(a1, b0, acc10);
            acc11 = fmaf(a1, b1, acc11);
        }
        __syncthreads();
    }
    const float inv = 1.0f / (NSAMP - 1);
    int c = c0 + ty * 2, d = d0 + tx * 2;
    float mc0 = mean[w*128 + c],     mc1 = mean[w*128 + c + 1];
    float md0 = mean[w*128 + d],     md1 = mean[w*128 + d + 1];
    _Float16* o = covah + ((size_t)w * 128 + c) * 128 + d;
    o[0]   = (_Float16)((acc00 - (float)NSAMP * mc0 * md0) * inv);
    o[1]   = (_Float16)((acc01 - (float)NSAMP * mc0 * md1) * inv);
    o[128] = (_Float16)((acc10 - (float)NSAMP * mc1 * md0) * inv);
    o[129] = (_Float16)((acc11 - (float)NSAMP * mc1 * md1) * inv);
}

#define LDQ 136
__global__ __launch_bounds__(512) void sim_kernel_f(const float* __restrict__ x1,
                                                    const _Float16* __restrict__ Ch,
                                                    const float* __restrict__ rn,
                                                    float* __restrict__ out) {
    __shared__ _Float16 qT[128][LDQ];
    __shared__ float simbuf[2][128];
    int tid = threadIdx.x;
    int bq  = blockIdx.x;
    int b   = bq >> 3;
    int i0  = (bq & 7) * 128;
    {
        int c  = tid >> 2;
        int iq = (tid & 3) * 32;
        const float* src = x1 + ((size_t)b * C_CH + c) * HW + i0 + iq;
        float scale = rn[b * C_CH + c];
        #pragma unroll
        for (int j4 = 0; j4 < 8; ++j4) {
            f32x4 v = *(const f32x4*)(src + j4 * 4);
            qT[iq + j4*4 + 0][c] = (_Float16)(v[0] * scale);
            qT[iq + j4*4 + 1][c] = (_Float16)(v[1] * scale);
            qT[iq + j4*4 + 2][c] = (_Float16)(v[2] * scale);
            qT[iq + j4*4 + 3][c] = (_Float16)(v[3] * scale);
        }
    }
    __syncthreads();
    int lane = tid & 63;
    int wv   = tid >> 6;
    int mh   = wv >> 2;
    int nq   = wv & 3;
    int d0w  = mh * 64;
    int iw   = nq * 32;
    int lr   = lane & 15;
    int lg   = lane >> 4;
    float qd[4][2][4];
    #pragma unroll
    for (int m = 0; m < 4; ++m)
        #pragma unroll
        for (int n = 0; n < 2; ++n) {
            half4 hq = *(const half4*)&qT[iw + n*16 + lr][d0w + m*16 + lg*4];
            qd[m][n][0] = (float)hq[0];
            qd[m][n][1] = (float)hq[1];
            qd[m][n][2] = (float)hq[2];
            qd[m][n][3] = (float)hq[3];
        }
    for (int w = 0; w < W_CLS; ++w) {
        const _Float16* Cw = Ch + (size_t)w * C_CH * C_CH;
        half8 A[4][4];
        #pragma unroll
        for (int m = 0; m < 4; ++m)
            #pragma unroll
            for (int k = 0; k < 4; ++k)
                A[m][k] = *(const half8*)(Cw + (size_t)(d0w + m*16 + lr) * C_CH + k*32 + lg*8);
        f32x4 acc[4][2];
        #pragma unroll
        for (int m = 0; m < 4; ++m)
            #pragma unroll
            for (int n = 0; n < 2; ++n)
                acc[m][n] = (f32x4){0.f, 0.f, 0.f, 0.f};
        #pragma unroll
        for (int k = 0; k < 4; ++k) {
            #pragma unroll
            for (int n = 0; n < 2; ++n) {
                half8 Bf = *(const half8*)&qT[iw + n*16 + lr][k*32 + lg*8];
                #pragma unroll
                for (int m = 0; m < 4; ++m)
                    acc[m][n] = __builtin_amdgcn_mfma_f32_16x16x32_f16(A[m][k], Bf, acc[m][n], 0, 0, 0);
            }
        }
        float s0 = 0.f, s1 = 0.f;
        #pragma unroll
        for (int m = 0; m < 4; ++m) {
            #pragma unroll
            for (int r = 0; r < 4; ++r) {
                s0 = fmaf(qd[m][0][r], acc[m][0][r], s0);
                s1 = fmaf(qd[m][1][r], acc[m][1][r], s1);
            }
        }
        s0 += __shfl_xor(s0, 16); s0 += __shfl_xor(s0, 32);
        s1 += __shfl_xor(s1, 16); s1 += __shfl_xor(s1, 32);
        if (lane < 16) {
            simbuf[mh][iw + 0*16 + lane] = s0;
            simbuf[mh][iw + 1*16 + lane] = s1;
        }
        __syncthreads();
        if (tid < 128)
            out[((size_t)b * W_CLS + w) * HW + i0 + tid] = simbuf[0][tid] + simbuf[1][tid];
        __syncthreads();
    }
}

// ================= host =================

extern "C" void kernel_launch(void* const* d_in, const int* in_sizes, int n_in,
                              void* d_out, int out_size, void* d_ws, size_t ws_size,
                              hipStream_t stream) {
    (void)in_sizes; (void)n_in; (void)out_size;
    const float* x1 = (const float*)d_in[0];   // [256,128,32,32]
    const float* x2 = (const float*)d_in[1];   // [16,8,128,32,32]
    float* out = (float*)d_out;

    char* ws = (char*)d_ws;
    const size_t OFF_QF  = 0;                          // 64 MB
    const size_t OFF_PG  = 67108864;                   // 512*16384 fp16 = 16.78 MB
    const size_t OFF_PM  = OFF_PG  + 16777216;         // 16*32*128 f32 = 256 KB
    const size_t OFF_UH  = OFF_PM  + 262144;           // 512 KB
    const size_t OFF_RN  = OFF_UH  + 524288;           // 128 KB (fallback only)
    const size_t NEED    = OFF_RN  + 131072;

    if (ws_size >= NEED) {
        _Float16* qf  = (_Float16*)(ws + OFF_QF);
        _Float16* PGh = (_Float16*)(ws + OFF_PG);
        float*    pm  = (float*)(ws + OFF_PM);
        _Float16* Uh  = (_Float16*)(ws + OFF_UH);
        cova_kernel<<<512,  512, 0, stream>>>(x2, PGh, pm);
        qcr_kernel <<<384,  512, 0, stream>>>(x1, qf, PGh, pm, Uh);
        sim_kernel <<<1024, 256, 0, stream>>>(qf, Uh, out);
    } else {
        float*    mean = (float*)ws;
        float*    rn   = mean + W_CLS*C_CH;
        _Float16* Ch   = (_Float16*)(rn + B_Q*C_CH);
        mean_kernel_f<<<W_CLS*C_CH,  256, 0, stream>>>(x2, mean);
        cova_kernel_f<<<W_CLS*16,    256, 0, stream>>>(x2, mean, Ch);
        rnorm_kernel <<<B_Q*C_CH/4,  256, 0, stream>>>(x1, rn);
        sim_kernel_f <<<B_Q*8,       512, 0, stream>>>(x1, Ch, rn, out);
    }
}

// Round 18
// 158.710 us; speedup vs baseline: 1.2401x; 1.2401x over previous
//
#include <hip/hip_runtime.h>

typedef _Float16 half8 __attribute__((ext_vector_type(8)));
typedef _Float16 half4 __attribute__((ext_vector_type(4)));
typedef float    f32x4 __attribute__((ext_vector_type(4)));

#define W_CLS 16
#define SHOT  8
#define C_CH  128
#define HW    1024
#define NSAMP (SHOT*HW)   /* 8192 */
#define B_Q   256
#define KSPL  32           /* cova K-splits (K=256 per block) */

// async global->LDS, 16B per lane; LDS dest = wave-uniform base (+lane*16 by HW)
__device__ __forceinline__ void gload_lds16(const _Float16* g, _Float16* l) {
    __builtin_amdgcn_global_load_lds((const __attribute__((address_space(1))) unsigned int*)g,
                                     (__attribute__((address_space(3))) unsigned int*)l,
                                     16, 0, 0);
}

// ================= primary path =================

// ---- cova: per (w, k-split) partial gram via fp16 MFMA + mean partials --------
// grid 512 = 16 w x 32 ks (K=256 per block -> 2 blocks/CU), block 512; fp16 PG.
__global__ __launch_bounds__(512) void cova_kernel(const float* __restrict__ x2,
                                                   _Float16* __restrict__ PGh,
                                                   float* __restrict__ pmean) {
    __shared__ _Float16 XT[2][128*72];
    __shared__ float mred[128][4];
    int tid = threadIdx.x;

    int w = blockIdx.x >> 5, ks = blockIdx.x & 31;
    int s = ks >> 2, p00 = (ks & 3) * 256;
    int c = tid >> 2, ph = (tid & 3) * 16;
    const float* src = x2 + (((size_t)(w*SHOT + s))*C_CH + c)*HW + p00 + ph;
    int lane = tid & 63, wv = tid >> 6;
    int lr = lane & 15, lg = lane >> 4;
    int mt0 = (wv & 3)*2, nt0 = (wv >> 2)*4;

    float msum = 0.f;
    f32x4 acc[2][4];
    #pragma unroll
    for (int mm = 0; mm < 2; ++mm)
        #pragma unroll
        for (int nn = 0; nn < 4; ++nn) acc[mm][nn] = (f32x4){0.f,0.f,0.f,0.f};

    float4 rg[4];
    #pragma unroll
    for (int j = 0; j < 4; ++j) rg[j] = *(const float4*)(src + j*4);
    #pragma unroll
    for (int j = 0; j < 4; ++j) {
        msum += rg[j].x + rg[j].y + rg[j].z + rg[j].w;
        half4 h = {(_Float16)rg[j].x, (_Float16)rg[j].y, (_Float16)rg[j].z, (_Float16)rg[j].w};
        *(half4*)(&XT[0][c*72 + ph + j*4]) = h;
    }
    __syncthreads();

    for (int ch = 0; ch < 4; ++ch) {
        int buf = ch & 1;
        if (ch < 3) {
            #pragma unroll
            for (int j = 0; j < 4; ++j) rg[j] = *(const float4*)(src + (ch+1)*64 + j*4);
        }
        const _Float16* xb = XT[buf];
        #pragma unroll
        for (int kk = 0; kk < 2; ++kk) {
            half8 Bv[4], Av[2];
            #pragma unroll
            for (int nn = 0; nn < 4; ++nn)
                Bv[nn] = *(const half8*)(xb + ((nt0+nn)*16 + lr)*72 + kk*32 + lg*8);
            #pragma unroll
            for (int mm = 0; mm < 2; ++mm)
                Av[mm] = *(const half8*)(xb + ((mt0+mm)*16 + lr)*72 + kk*32 + lg*8);
            #pragma unroll
            for (int mm = 0; mm < 2; ++mm)
                #pragma unroll
                for (int nn = 0; nn < 4; ++nn)
                    acc[mm][nn] = __builtin_amdgcn_mfma_f32_16x16x32_f16(Av[mm], Bv[nn], acc[mm][nn], 0,0,0);
        }
        if (ch < 3) {
            #pragma unroll
            for (int j = 0; j < 4; ++j) {
                msum += rg[j].x + rg[j].y + rg[j].z + rg[j].w;
                half4 h = {(_Float16)rg[j].x, (_Float16)rg[j].y, (_Float16)rg[j].z, (_Float16)rg[j].w};
                *(half4*)(&XT[buf^1][c*72 + ph + j*4]) = h;
            }
        }
        __syncthreads();
    }

    mred[c][tid & 3] = msum;
    __syncthreads();
    if (tid < 128)
        pmean[((size_t)w*KSPL + ks)*128 + tid] = mred[tid][0]+mred[tid][1]+mred[tid][2]+mred[tid][3];

    _Float16* pg = PGh + ((size_t)w*KSPL + ks)*16384;
    #pragma unroll
    for (int mm = 0; mm < 2; ++mm)
        #pragma unroll
        for (int nn = 0; nn < 4; ++nn)
            #pragma unroll
            for (int r = 0; r < 4; ++r) {
                int cr = (mt0+mm)*16 + lg*4 + r;
                int d  = (nt0+nn)*16 + lr;
                pg[cr*128 + d] = (_Float16)acc[mm][nn][r];
            }
}

// ---- qcr: blocks 0..255 = per-b fused rnorm + normalize + fp16 fragment repack;
// ----      blocks 256..383 = cova_reduce (overlaps with qconv's BW phase).
__global__ __launch_bounds__(512) void qcr_kernel(const float* __restrict__ x1,
                                                  _Float16* __restrict__ qf,
                                                  const _Float16* __restrict__ PGh,
                                                  const float* __restrict__ pmean,
                                                  _Float16* __restrict__ Uh) {
    if (blockIdx.x >= 256) {
        // ------------- cova_reduce part (512 threads) -------------
        __shared__ float ms[128];
        int t = threadIdx.x;
        int bid = blockIdx.x - 256;
        int w = bid >> 3, rg = bid & 7;
        if (t < 128) {
            float sum = 0.f;
            for (int ks = 0; ks < KSPL; ++ks) sum += pmean[((size_t)w*KSPL + ks)*128 + t];
            ms[t] = sum * (1.0f/NSAMP);
        }
        __syncthreads();
        const _Float16* pg = PGh + (size_t)w*KSPL*16384;
        #pragma unroll
        for (int it = 0; it < 4; ++it) {
            int e = it*512 + t;
            int r = rg*16 + (e >> 7), d = e & 127;
            float g = 0.f;
            for (int ks = 0; ks < KSPL; ++ks) g += (float)pg[(size_t)ks*16384 + r*128 + d];
            float val = (g - (float)NSAMP*ms[r]*ms[d]) * (1.0f/(NSAMP-1));
            float uval = (d > r) ? val : ((d == r) ? 0.5f*val : 0.0f);
            Uh[((size_t)w*128 + r)*128 + d] = (_Float16)uval;
        }
        return;
    }

    // ------------- qconv part: one block per b, rn computed in-block -------------
    __shared__ _Float16 T[128*258];
    __shared__ float rnL[128];
    int tid = threadIdx.x, lane = tid & 63, wv = tid >> 6;
    int b = blockIdx.x;
    const float* xb = x1 + (size_t)b * C_CH * HW;

    // pass A: rn per channel (full-row square sums), x1 slab -> L2
    #pragma unroll
    for (int cc = 0; cc < 16; ++cc) {
        int c = wv*16 + cc;
        const f32x4* row = (const f32x4*)(xb + (size_t)c * HW);
        float s = 0.f;
        #pragma unroll
        for (int j = 0; j < 4; ++j) {
            f32x4 v = row[lane + j*64];
            s += v[0]*v[0] + v[1]*v[1] + v[2]*v[2] + v[3]*v[3];
        }
        #pragma unroll
        for (int off = 32; off; off >>= 1) s += __shfl_xor(s, off, 64);
        if (lane == 0) rnL[c] = 1.0f / sqrtf(s);
    }
    __syncthreads();

    // pass B: per 256-px chunk (L2-hot re-read): stage normalized fp16, emit frags
    for (int ic = 0; ic < 4; ++ic) {
        #pragma unroll
        for (int cc = 0; cc < 16; ++cc) {
            int c = wv*16 + cc;
            f32x4 v = *(const f32x4*)(xb + (size_t)c * HW + ic*256 + lane*4);
            float sc = rnL[c];
            half4 h = {(_Float16)(v[0]*sc), (_Float16)(v[1]*sc),
                       (_Float16)(v[2]*sc), (_Float16)(v[3]*sc)};
            *(half4*)(&T[c*258 + lane*4]) = h;
        }
        __syncthreads();
        #pragma unroll
        for (int it = 0; it < 8; ++it) {
            int slot = it*512 + tid;          // 16 tiles x 4 kk x 64 lanes
            int tl = slot >> 8;
            int kk = (slot >> 6) & 3;
            int ln = slot & 63;
            int i_loc = tl*16 + (ln & 15);
            int c0 = kk*32 + (ln >> 4)*8;
            half8 pk;
            #pragma unroll
            for (int e = 0; e < 8; ++e) pk[e] = T[(c0+e)*258 + i_loc];
            *(half8*)(qf + (((size_t)b*64 + ic*16 + tl)*4 + kk)*512 + ln*8) = pk;
        }
        __syncthreads();
    }
}

// ---- sim (R16 verbatim — best measured 94.0 us): LDS-staged, 4 waves = 4 w,
// full triangle per wave, tree-reduced diag tail, 3 blocks/CU.
// grid 1024: b = bid&255 (4 readers of b -> same XCD), wg = bid>>8 -> w-quad.
#define TR 4
__global__ __launch_bounds__(256, 3) void sim_kernel(const _Float16* __restrict__ qf,
                                                     const _Float16* __restrict__ Uh,
                                                     float* __restrict__ out) {
    __shared__ _Float16 stage[2][TR*2048];     // 2 x 16 KB
    int tid = threadIdx.x, lane = tid & 63, wv = tid >> 6;
    int lr = lane & 15, lg = lane >> 4;
    int b = blockIdx.x & 255, wg = blockIdx.x >> 8;
    int w = wg*4 + wv;

    // A: 20 upper-triangular fragments (m <= 2kk+1), loaded once, L2-resident
    half8 A[20];
    {
        const _Float16* Ub = Uh + (size_t)w*C_CH*C_CH + (size_t)lr*C_CH + lg*8;
        int idx = 0;
        #pragma unroll
        for (int kk = 0; kk < 4; ++kk)
            #pragma unroll
            for (int m = 0; m <= 2*kk+1; ++m) {
                A[idx] = *(const half8*)(Ub + (size_t)m*16*C_CH + kk*32);
                ++idx;
            }
    }

    const _Float16* qfb = qf + (size_t)b * 131072;   // 64 tiles * 2048 halves

    // prologue: stage round 0 -> buf 0 (256 thr x 4 x 16B = 16KB)
    #pragma unroll
    for (int k = 0; k < 4; ++k)
        gload_lds16(qfb + tid*8 + k*2048, &stage[0][tid*8 + k*2048]);
    __syncthreads();

    int offD0 = (lg>>1)*128 + lr*8 + (lg&1)*4;   // + (m>>1)*512 + (m&1)*256
    float* ob = out + ((size_t)b*W_CLS + w)*HW;
    int cur = 0;

    for (int r = 0; r < 16; ++r) {
        if (r < 15) {
            const _Float16* gsrc = qfb + (size_t)(r+1)*(TR*2048);
            #pragma unroll
            for (int k = 0; k < 4; ++k)
                gload_lds16(gsrc + tid*8 + k*2048, &stage[cur^1][tid*8 + k*2048]);
        }
        #pragma unroll
        for (int ti = 0; ti < TR; ++ti) {
            const _Float16* tb = &stage[cur][ti*2048];
            half8 B[4];
            #pragma unroll
            for (int kk = 0; kk < 4; ++kk)
                B[kk] = *(const half8*)(tb + kk*512 + lane*8);
            half4 D[8];
            #pragma unroll
            for (int m = 0; m < 8; ++m)
                D[m] = *(const half4*)(tb + (m>>1)*512 + (m&1)*256 + offD0);
            f32x4 acc[8];
            #pragma unroll
            for (int m = 0; m < 8; ++m) acc[m] = (f32x4){0.f,0.f,0.f,0.f};
            __builtin_amdgcn_s_setprio(1);
            {
                int idx = 0;
                #pragma unroll
                for (int kk = 0; kk < 4; ++kk)
                    #pragma unroll
                    for (int m = 0; m <= 2*kk+1; ++m) {
                        acc[m] = __builtin_amdgcn_mfma_f32_16x16x32_f16(A[idx], B[kk], acc[m], 0, 0, 0);
                        ++idx;
                    }
            }
            __builtin_amdgcn_s_setprio(0);
            // diag tail: 4 independent partials + tree combine (short dep chain)
            float p0 = 0.f, p1 = 0.f, p2 = 0.f, p3 = 0.f;
            #pragma unroll
            for (int m = 0; m < 8; ++m) {
                p0 = fmaf((float)D[m][0], acc[m][0], p0);
                p1 = fmaf((float)D[m][1], acc[m][1], p1);
                p2 = fmaf((float)D[m][2], acc[m][2], p2);
                p3 = fmaf((float)D[m][3], acc[m][3], p3);
            }
            float s = (p0 + p1) + (p2 + p3);
            s += __shfl_xor(s, 16, 64);
            s += __shfl_xor(s, 32, 64);
            if (lane < 16) ob[(r*TR + ti)*16 + lr] = 2.0f * s;
        }
        __syncthreads();   // all waves done with buf cur; next-round stage landed
        cur ^= 1;
    }
}
#undef TR

// ================= fallback path (small ws) =================

__global__ __launch_bounds__(256) void rnorm_kernel(const float* __restrict__ x1,
                                                    float* __restrict__ rn) {
    int row  = blockIdx.x * 4 + (threadIdx.x >> 6);
    int lane = threadIdx.x & 63;
    const float4* p = (const float4*)(x1 + (size_t)row * HW);
    float s = 0.f;
    #pragma unroll
    for (int it = 0; it < 4; ++it) {
        float4 v = p[lane + it * 64];
        s += v.x*v.x + v.y*v.y + v.z*v.z + v.w*v.w;
    }
    for (int off = 32; off; off >>= 1) s += __shfl_down(s, off, 64);
    if (lane == 0) rn[row] = 1.0f / sqrtf(s);
}

__global__ __launch_bounds__(256) void mean_kernel_f(const float* __restrict__ x2,
                                                     float* __restrict__ mean) {
    int wc = blockIdx.x;
    int w  = wc >> 7, c = wc & 127;
    const float* base = x2 + ((size_t)(w * SHOT) * C_CH + c) * HW;
    int tid = threadIdx.x;
    float sum = 0.f;
    for (int s = 0; s < SHOT; ++s) {
        const float* row = base + (size_t)s * C_CH * HW;
        for (int p = tid; p < HW; p += 256) sum += row[p];
    }
    for (int off = 32; off; off >>= 1) sum += __shfl_down(sum, off, 64);
    __shared__ float red[4];
    int lane = tid & 63, wv = tid >> 6;
    if (lane == 0) red[wv] = sum;
    __syncthreads();
    if (tid == 0) mean[wc] = (red[0] + red[1] + red[2] + red[3]) * (1.0f / NSAMP);
}

__global__ __launch_bounds__(256) void cova_kernel_f(const float* __restrict__ x2,
                                                     const float* __restrict__ mean,
                                                     _Float16* __restrict__ covah) {
    int bid = blockIdx.x;
    int w  = bid >> 4;
    int c0 = ((bid >> 2) & 3) * 32;
    int d0 = (bid & 3) * 32;
    __shared__ float As[32][33];
    __shared__ float Bs[32][33];
    int tid = threadIdx.x;
    int ty = tid >> 4, tx = tid & 15;
    int lrr = tid >> 3, lc = (tid & 7) * 4;
    const float* base = x2 + (size_t)w * SHOT * C_CH * HW;
    float acc00 = 0.f, acc01 = 0.f, acc10 = 0.f, acc11 = 0.f;
    for (int k0 = 0; k0 < NSAMP; k0 += 32) {
        int s = k0 >> 10, p = k0 & 1023;
        const float4 a4 = *(const float4*)(base + ((size_t)s * C_CH + (c0 + lrr)) * HW + p + lc);
        const float4 b4 = *(const float4*)(base + ((size_t)s * C_CH + (d0 + lrr)) * HW + p + lc);
        As[lrr][lc+0] = a4.x; As[lrr][lc+1] = a4.y; As[lrr][lc+2] = a4.z; As[lrr][lc+3] = a4.w;
        Bs[lrr][lc+0] = b4.x; Bs[lrr][lc+1] = b4.y; Bs[lrr][lc+2] = b4.z; Bs[lrr][lc+3] = b4.w;
        __syncthreads();
        #pragma unroll
        for (int kk = 0; kk < 32; ++kk) {
            float a0 = As[ty*2][kk],   a1 = As[ty*2+1][kk];
            float b0 = Bs[tx*2][kk],   b1 = Bs[tx*2+1][kk];
            acc00 = fmaf(a0, b0, acc00);
            acc01 = fmaf(a0, b1, acc01);
            acc10 = fmaf(a1, b0, acc10);
            acc11 = fmaf(a1, b1, acc11);
        }
        __syncthreads();
    }
    const float inv = 1.0f / (NSAMP - 1);
    int c = c0 + ty * 2, d = d0 + tx * 2;
    float mc0 = mean[w*128 + c],     mc1 = mean[w*128 + c + 1];
    float md0 = mean[w*128 + d],     md1 = mean[w*128 + d + 1];
    _Float16* o = covah + ((size_t)w * 128 + c) * 128 + d;
    o[0]   = (_Float16)((acc00 - (float)NSAMP * mc0 * md0) * inv);
    o[1]   = (_Float16)((acc01 - (float)NSAMP * mc0 * md1) * inv);
    o[128] = (_Float16)((acc10 - (float)NSAMP * mc1 * md0) * inv);
    o[129] = (_Float16)((acc11 - (float)NSAMP * mc1 * md1) * inv);
}

#define LDQ 136
__global__ __launch_bounds__(512) void sim_kernel_f(const float* __restrict__ x1,
                                                    const _Float16* __restrict__ Ch,
                                                    const float* __restrict__ rn,
                                                    float* __restrict__ out) {
    __shared__ _Float16 qT[128][LDQ];
    __shared__ float simbuf[2][128];
    int tid = threadIdx.x;
    int bq  = blockIdx.x;
    int b   = bq >> 3;
    int i0  = (bq & 7) * 128;
    {
        int c  = tid >> 2;
        int iq = (tid & 3) * 32;
        const float* src = x1 + ((size_t)b * C_CH + c) * HW + i0 + iq;
        float scale = rn[b * C_CH + c];
        #pragma unroll
        for (int j4 = 0; j4 < 8; ++j4) {
            f32x4 v = *(const f32x4*)(src + j4 * 4);
            qT[iq + j4*4 + 0][c] = (_Float16)(v[0] * scale);
            qT[iq + j4*4 + 1][c] = (_Float16)(v[1] * scale);
            qT[iq + j4*4 + 2][c] = (_Float16)(v[2] * scale);
            qT[iq + j4*4 + 3][c] = (_Float16)(v[3] * scale);
        }
    }
    __syncthreads();
    int lane = tid & 63;
    int wv   = tid >> 6;
    int mh   = wv >> 2;
    int nq   = wv & 3;
    int d0w  = mh * 64;
    int iw   = nq * 32;
    int lr   = lane & 15;
    int lg   = lane >> 4;
    float qd[4][2][4];
    #pragma unroll
    for (int m = 0; m < 4; ++m)
        #pragma unroll
        for (int n = 0; n < 2; ++n) {
            half4 hq = *(const half4*)&qT[iw + n*16 + lr][d0w + m*16 + lg*4];
            qd[m][n][0] = (float)hq[0];
            qd[m][n][1] = (float)hq[1];
            qd[m][n][2] = (float)hq[2];
            qd[m][n][3] = (float)hq[3];
        }
    for (int w = 0; w < W_CLS; ++w) {
        const _Float16* Cw = Ch + (size_t)w * C_CH * C_CH;
        half8 A[4][4];
        #pragma unroll
        for (int m = 0; m < 4; ++m)
            #pragma unroll
            for (int k = 0; k < 4; ++k)
                A[m][k] = *(const half8*)(Cw + (size_t)(d0w + m*16 + lr) * C_CH + k*32 + lg*8);
        f32x4 acc[4][2];
        #pragma unroll
        for (int m = 0; m < 4; ++m)
            #pragma unroll
            for (int n = 0; n < 2; ++n)
                acc[m][n] = (f32x4){0.f, 0.f, 0.f, 0.f};
        #pragma unroll
        for (int k = 0; k < 4; ++k) {
            #pragma unroll
            for (int n = 0; n < 2; ++n) {
                half8 Bf = *(const half8*)&qT[iw + n*16 + lr][k*32 + lg*8];
                #pragma unroll
                for (int m = 0; m < 4; ++m)
                    acc[m][n] = __builtin_amdgcn_mfma_f32_16x16x32_f16(A[m][k], Bf, acc[m][n], 0, 0, 0);
            }
        }
        float s0 = 0.f, s1 = 0.f;
        #pragma unroll
        for (int m = 0; m < 4; ++m) {
            #pragma unroll
            for (int r = 0; r < 4; ++r) {
                s0 = fmaf(qd[m][0][r], acc[m][0][r], s0);
                s1 = fmaf(qd[m][1][r], acc[m][1][r], s1);
            }
        }
        s0 += __shfl_xor(s0, 16); s0 += __shfl_xor(s0, 32);
        s1 += __shfl_xor(s1, 16); s1 += __shfl_xor(s1, 32);
        if (lane < 16) {
            simbuf[mh][iw + 0*16 + lane] = s0;
            simbuf[mh][iw + 1*16 + lane] = s1;
        }
        __syncthreads();
        if (tid < 128)
            out[((size_t)b * W_CLS + w) * HW + i0 + tid] = simbuf[0][tid] + simbuf[1][tid];
        __syncthreads();
    }
}

// ================= host =================

extern "C" void kernel_launch(void* const* d_in, const int* in_sizes, int n_in,
                              void* d_out, int out_size, void* d_ws, size_t ws_size,
                              hipStream_t stream) {
    (void)in_sizes; (void)n_in; (void)out_size;
    const float* x1 = (const float*)d_in[0];   // [256,128,32,32]
    const float* x2 = (const float*)d_in[1];   // [16,8,128,32,32]
    float* out = (float*)d_out;

    char* ws = (char*)d_ws;
    const size_t OFF_QF  = 0;                          // 64 MB
    const size_t OFF_PG  = 67108864;                   // 512*16384 fp16 = 16.78 MB
    const size_t OFF_PM  = OFF_PG  + 16777216;         // 16*32*128 f32 = 256 KB
    const size_t OFF_UH  = OFF_PM  + 262144;           // 512 KB
    const size_t OFF_RN  = OFF_UH  + 524288;           // 128 KB (fallback only)
    const size_t NEED    = OFF_RN  + 131072;

    if (ws_size >= NEED) {
        _Float16* qf  = (_Float16*)(ws + OFF_QF);
        _Float16* PGh = (_Float16*)(ws + OFF_PG);
        float*    pm  = (float*)(ws + OFF_PM);
        _Float16* Uh  = (_Float16*)(ws + OFF_UH);
        cova_kernel<<<512,  512, 0, stream>>>(x2, PGh, pm);
        qcr_kernel <<<384,  512, 0, stream>>>(x1, qf, PGh, pm, Uh);
        sim_kernel <<<1024, 256, 0, stream>>>(qf, Uh, out);
    } else {
        float*    mean = (float*)ws;
        float*    rn   = mean + W_CLS*C_CH;
        _Float16* Ch   = (_Float16*)(rn + B_Q*C_CH);
        mean_kernel_f<<<W_CLS*C_CH,  256, 0, stream>>>(x2, mean);
        cova_kernel_f<<<W_CLS*16,    256, 0, stream>>>(x2, mean, Ch);
        rnorm_kernel <<<B_Q*C_CH/4,  256, 0, stream>>>(x1, rn);
        sim_kernel_f <<<B_Q*8,       512, 0, stream>>>(x1, Ch, rn, out);
    }
}